// Round 1
// baseline (127.223 us; speedup 1.0000x reference)
//
#include <hip/hip_runtime.h>

#define N_PROP 1000
#define NCLS   91
#define KDET   100
#define SORT_N 1024
#define SCORE_TH 0.05f
#define NMS_TH   0.5f
#define MIN_SIZE 1.0f
#define BBOX_CLIP 4.135166556742356f  // log(1000/16)

// Kernel 1: per-row softmax stats: stats[i] = rowmax, stats[N+i] = 1/sum(exp(x-max))
__global__ void softmax_stats_kernel(const float* __restrict__ logit,
                                     float* __restrict__ stats) {
    int row = blockIdx.x * blockDim.x + threadIdx.x;
    if (row >= N_PROP) return;
    const float* p = logit + row * NCLS;
    float m = -1e30f;
    for (int c = 0; c < NCLS; ++c) m = fmaxf(m, p[c]);
    float s = 0.0f;
    for (int c = 0; c < NCLS; ++c) s += expf(p[c] - m);
    stats[row] = m;
    stats[N_PROP + row] = 1.0f / s;
}

// Kernel 2: one block per class (classes 1..90).
__global__ __launch_bounds__(256) void per_class_kernel(
    const float* __restrict__ logit,
    const float* __restrict__ boxreg,
    const float* __restrict__ proposal,
    const int* __restrict__ ih_p,
    const int* __restrict__ iw_p,
    const float* __restrict__ stats,
    float* __restrict__ out) {
    const int c   = blockIdx.x + 1;   // class index 1..90
    const int tid = threadIdx.x;
    const float W = (float)(*iw_p);
    const float H = (float)(*ih_p);

    __shared__ float  s_key[SORT_N];
    __shared__ int    s_val[SORT_N];
    __shared__ float4 s_box[SORT_N];    // decoded+clipped boxes, original index order
    __shared__ float4 s_sbox[SORT_N];   // boxes in sorted order (first V only)
    __shared__ int    s_keep[SORT_N];
    __shared__ int    s_outpos[KDET];
    __shared__ int    s_V, s_nout;

    // ---- compute score / decode / clip / validity ----
    for (int i = tid; i < SORT_N; i += 256) {
        if (i < N_PROP) {
            float l = logit[i * NCLS + c];
            float score = expf(l - stats[i]) * stats[N_PROP + i];

            const float* pr = proposal + i * 4;
            float px1 = pr[0], py1 = pr[1], px2 = pr[2], py2 = pr[3];
            float w  = px2 - px1, h = py2 - py1;
            float cx = px1 + 0.5f * w, cy = py1 + 0.5f * h;

            const float* d = boxreg + i * (NCLS * 4) + c * 4;
            float dx = d[0] / 10.0f;
            float dy = d[1] / 10.0f;
            float dw = fminf(d[2] / 5.0f, BBOX_CLIP);
            float dh = fminf(d[3] / 5.0f, BBOX_CLIP);
            float pcx = dx * w + cx, pcy = dy * h + cy;
            float pw  = expf(dw) * w, ph = expf(dh) * h;
            float x1 = pcx - 0.5f * pw, y1 = pcy - 0.5f * ph;
            float x2 = pcx + 0.5f * pw, y2 = pcy + 0.5f * ph;
            // clip to image
            x1 = fminf(fmaxf(x1, 0.0f), W);
            x2 = fminf(fmaxf(x2, 0.0f), W);
            y1 = fminf(fmaxf(y1, 0.0f), H);
            y2 = fminf(fmaxf(y2, 0.0f), H);
            bool valid = (score >= SCORE_TH) && ((x2 - x1) >= MIN_SIZE) && ((y2 - y1) >= MIN_SIZE);
            s_key[i] = valid ? score : -1.0f;
            s_val[i] = i;
            s_box[i] = make_float4(x1, y1, x2, y2);
        } else {
            s_key[i] = -2.0f;   // padding sorts to the very end
            s_val[i] = i;
        }
    }
    __syncthreads();

    // ---- bitonic sort, descending by key ----
    for (int k = 2; k <= SORT_N; k <<= 1) {
        for (int j = k >> 1; j > 0; j >>= 1) {
            for (int t = tid; t < SORT_N; t += 256) {
                int ixj = t ^ j;
                if (ixj > t) {
                    bool up = ((t & k) == 0);
                    float a = s_key[t], b = s_key[ixj];
                    bool sw = up ? (a < b) : (a > b);
                    if (sw) {
                        s_key[t] = b; s_key[ixj] = a;
                        int va = s_val[t]; s_val[t] = s_val[ixj]; s_val[ixj] = va;
                    }
                }
            }
            __syncthreads();
        }
    }

    // ---- count valid prefix V (keys >= SCORE_TH sorted to front) ----
    if (tid == 0) s_V = 0;
    __syncthreads();
    for (int t = tid; t < SORT_N; t += 256) {
        if (s_key[t] >= SCORE_TH && (t == SORT_N - 1 || s_key[t + 1] < SCORE_TH))
            s_V = t + 1;
    }
    __syncthreads();
    const int V = s_V;

    // ---- gather sorted boxes, init keep ----
    for (int t = tid; t < V; t += 256) {
        s_sbox[t] = s_box[s_val[t]];
        s_keep[t] = 1;
    }
    __syncthreads();

    // ---- greedy NMS over valid prefix ----
    for (int i = 0; i + 1 < V; ++i) {
        if (s_keep[i]) {
            float4 bi = s_sbox[i];
            float areai = (bi.z - bi.x) * (bi.w - bi.y);
            for (int t = i + 1 + tid; t < V; t += 256) {
                if (s_keep[t]) {
                    float4 bj = s_sbox[t];
                    float lx = fmaxf(bi.x, bj.x), ly = fmaxf(bi.y, bj.y);
                    float rx = fminf(bi.z, bj.z), ry = fminf(bi.w, bj.w);
                    float iw = fmaxf(rx - lx, 0.0f), ihh = fmaxf(ry - ly, 0.0f);
                    float inter = iw * ihh;
                    float areaj = (bj.z - bj.x) * (bj.w - bj.y);
                    float uni = areai + areaj - inter;
                    float iou = inter / fmaxf(uni, 1e-6f);
                    if (iou > NMS_TH) s_keep[t] = 0;
                }
            }
        }
        __syncthreads();
    }

    // ---- compact kept entries (serial; V is small) ----
    if (tid == 0) {
        int cnt = 0;
        for (int t = 0; t < V && cnt < KDET; ++t)
            if (s_keep[t]) s_outpos[cnt++] = t;
        s_nout = cnt;
    }
    __syncthreads();
    const int nout = s_nout;

    // ---- write output: dets [9000,5] then labels [9000] (as float) ----
    float* dets   = out;
    float* labels = out + (NCLS - 1) * KDET * 5;
    const int rowbase = blockIdx.x * KDET;
    for (int t = tid; t < KDET; t += 256) {
        float x1 = 0.f, y1 = 0.f, x2 = 0.f, y2 = 0.f, sc = 0.f, lb = 0.f;
        if (t < nout) {
            int p = s_outpos[t];
            float4 b = s_sbox[p];
            x1 = b.x; y1 = b.y; x2 = b.z; y2 = b.w;
            sc = s_key[p];
            lb = (float)c;
        }
        float* r = dets + (size_t)(rowbase + t) * 5;
        r[0] = x1; r[1] = y1; r[2] = x2; r[3] = y2; r[4] = sc;
        labels[rowbase + t] = lb;
    }
}

extern "C" void kernel_launch(void* const* d_in, const int* in_sizes, int n_in,
                              void* d_out, int out_size, void* d_ws, size_t ws_size,
                              hipStream_t stream) {
    const float* logit    = (const float*)d_in[0];
    const float* boxreg   = (const float*)d_in[1];
    const float* proposal = (const float*)d_in[2];
    const int*   ih       = (const int*)d_in[3];
    const int*   iw       = (const int*)d_in[4];
    float* stats = (float*)d_ws;   // 2*N_PROP floats

    softmax_stats_kernel<<<(N_PROP + 255) / 256, 256, 0, stream>>>(logit, stats);
    per_class_kernel<<<NCLS - 1, 256, 0, stream>>>(logit, boxreg, proposal, ih, iw,
                                                   stats, (float*)d_out);
}

// Round 2
// 85.190 us; speedup vs baseline: 1.4934x; 1.4934x over previous
//
#include <hip/hip_runtime.h>
#include <math.h>

#define N_PROP 1000
#define NCLS   91
#define NCM1   90
#define KDET   100
#define SCORE_TH 0.05f
#define NMS_TH   0.5f
#define MIN_SIZE 1.0f
#define BBOX_CLIP 4.135166556742356f  // log(1000/16)

// ---- workspace layout (bytes) ----
// stats   f32[2*N_PROP]      @ 0        (rowmax, 1/sumexp)
// counters i32[96]           @ 8000
// keys    f32[NCM1*N_PROP]   @ 8384
// idxs    i32[NCM1*N_PROP]   @ 368384
// boxes   float4[NCM1*N_PROP]@ 728384   (16B aligned)
#define WS_STATS_OFF   0
#define WS_CNT_OFF     8000
#define WS_KEYS_OFF    8384
#define WS_IDXS_OFF    368384
#define WS_BOXES_OFF   728384

// K1: one wave per row. stats[row]=max, stats[N+row]=1/sum(exp(x-max)).
// Also zeros the per-class counters.
__global__ __launch_bounds__(256) void stats_kernel(const float* __restrict__ logit,
                                                    float* __restrict__ stats,
                                                    int* __restrict__ counters) {
    int gid  = blockIdx.x * blockDim.x + threadIdx.x;
    if (gid < NCM1) counters[gid] = 0;
    int wave = gid >> 6;
    int lane = gid & 63;
    if (wave >= N_PROP) return;
    const float* p = logit + wave * NCLS;
    float m = -INFINITY;
    for (int c = lane; c < NCLS; c += 64) m = fmaxf(m, p[c]);
    for (int d = 32; d > 0; d >>= 1) m = fmaxf(m, __shfl_xor(m, d));
    float s = 0.0f;
    for (int c = lane; c < NCLS; c += 64) s += expf(p[c] - m);
    for (int d = 32; d > 0; d >>= 1) s += __shfl_xor(s, d);
    if (lane == 0) {
        stats[wave] = m;
        stats[N_PROP + wave] = 1.0f / s;
    }
}

// K2: decode + filter + compact, fully parallel over 90000 (proposal,class) pairs.
__global__ __launch_bounds__(256) void decode_kernel(
    const float* __restrict__ logit,
    const float* __restrict__ boxreg,
    const float* __restrict__ proposal,
    const int* __restrict__ ih_p,
    const int* __restrict__ iw_p,
    const float* __restrict__ stats,
    int* __restrict__ counters,
    float* __restrict__ keys,
    int* __restrict__ idxs,
    float4* __restrict__ boxes) {
    int p = blockIdx.x * blockDim.x + threadIdx.x;
    if (p >= N_PROP * NCM1) return;
    int i   = p / NCM1;          // proposal
    int cm1 = p - i * NCM1;      // class-1
    int c   = cm1 + 1;

    const float W = (float)(*iw_p);
    const float H = (float)(*ih_p);

    float l = logit[i * NCLS + c];
    float score = expf(l - stats[i]) * stats[N_PROP + i];

    const float* pr = proposal + i * 4;
    float px1 = pr[0], py1 = pr[1], px2 = pr[2], py2 = pr[3];
    float w  = px2 - px1, h = py2 - py1;
    float cx = px1 + 0.5f * w, cy = py1 + 0.5f * h;

    const float* d = boxreg + (size_t)i * (NCLS * 4) + c * 4;
    float dx = d[0] / 10.0f;
    float dy = d[1] / 10.0f;
    float dw = fminf(d[2] / 5.0f, BBOX_CLIP);
    float dh = fminf(d[3] / 5.0f, BBOX_CLIP);
    float pcx = dx * w + cx, pcy = dy * h + cy;
    float pw  = expf(dw) * w, ph = expf(dh) * h;
    float x1 = pcx - 0.5f * pw, y1 = pcy - 0.5f * ph;
    float x2 = pcx + 0.5f * pw, y2 = pcy + 0.5f * ph;
    x1 = fminf(fmaxf(x1, 0.0f), W);
    x2 = fminf(fmaxf(x2, 0.0f), W);
    y1 = fminf(fmaxf(y1, 0.0f), H);
    y2 = fminf(fmaxf(y2, 0.0f), H);

    bool valid = (score >= SCORE_TH) && ((x2 - x1) >= MIN_SIZE) && ((y2 - y1) >= MIN_SIZE);
    if (valid) {
        int pos = atomicAdd(&counters[cm1], 1);
        if (pos < N_PROP) {
            int o = cm1 * N_PROP + pos;
            keys[o]  = score;
            idxs[o]  = i;
            boxes[o] = make_float4(x1, y1, x2, y2);
        }
    }
}

// K3: per-class rank-sort (O(V^2), V typically ~20) + greedy NMS + output.
__global__ __launch_bounds__(128) void nms_kernel(
    const int* __restrict__ counters,
    const float* __restrict__ keys,
    const int* __restrict__ idxs,
    const float4* __restrict__ boxes,
    float* __restrict__ out) {
    const int cm1 = blockIdx.x;
    const int tid = threadIdx.x;

    __shared__ float  s_key[N_PROP];
    __shared__ int    s_idx[N_PROP];
    __shared__ float4 s_box[N_PROP];
    __shared__ float  s_skey[N_PROP];
    __shared__ float4 s_sbox[N_PROP];
    __shared__ int    s_keep[N_PROP];
    __shared__ int    s_outpos[KDET];
    __shared__ int    s_nout;

    int V = counters[cm1];
    if (V > N_PROP) V = N_PROP;

    // load compacted entries
    for (int t = tid; t < V; t += 128) {
        int o = cm1 * N_PROP + t;
        s_key[t] = keys[o];
        s_idx[t] = idxs[o];
        s_box[t] = boxes[o];
    }
    __syncthreads();

    // rank sort: descending score, ties broken by ascending original index
    for (int t = tid; t < V; t += 128) {
        float kt = s_key[t];
        int   it = s_idx[t];
        int rank = 0;
        for (int j = 0; j < V; ++j) {
            float kj = s_key[j];
            rank += (kj > kt) || (kj == kt && s_idx[j] < it);
        }
        s_skey[rank] = kt;
        s_sbox[rank] = s_box[t];
    }
    __syncthreads();

    for (int t = tid; t < V; t += 128) s_keep[t] = 1;
    __syncthreads();

    // greedy NMS over sorted entries
    for (int i = 0; i + 1 < V; ++i) {
        if (s_keep[i]) {
            float4 bi = s_sbox[i];
            float areai = (bi.z - bi.x) * (bi.w - bi.y);
            for (int t = i + 1 + tid; t < V; t += 128) {
                if (s_keep[t]) {
                    float4 bj = s_sbox[t];
                    float lx = fmaxf(bi.x, bj.x), ly = fmaxf(bi.y, bj.y);
                    float rx = fminf(bi.z, bj.z), ry = fminf(bi.w, bj.w);
                    float iw = fmaxf(rx - lx, 0.0f), ihh = fmaxf(ry - ly, 0.0f);
                    float inter = iw * ihh;
                    float areaj = (bj.z - bj.x) * (bj.w - bj.y);
                    float uni = areai + areaj - inter;
                    float iou = inter / fmaxf(uni, 1e-6f);
                    if (iou > NMS_TH) s_keep[t] = 0;
                }
            }
        }
        __syncthreads();
    }

    // serial compaction (V small)
    if (tid == 0) {
        int cnt = 0;
        for (int t = 0; t < V && cnt < KDET; ++t)
            if (s_keep[t]) s_outpos[cnt++] = t;
        s_nout = cnt;
    }
    __syncthreads();
    const int nout = s_nout;

    // write output: dets [9000,5] then labels [9000] (as float)
    float* dets   = out;
    float* labels = out + NCM1 * KDET * 5;
    const int rowbase = cm1 * KDET;
    for (int t = tid; t < KDET; t += 128) {
        float x1 = 0.f, y1 = 0.f, x2 = 0.f, y2 = 0.f, sc = 0.f, lb = 0.f;
        if (t < nout) {
            int p = s_outpos[t];
            float4 b = s_sbox[p];
            x1 = b.x; y1 = b.y; x2 = b.z; y2 = b.w;
            sc = s_skey[p];
            lb = (float)(cm1 + 1);
        }
        float* r = dets + (size_t)(rowbase + t) * 5;
        r[0] = x1; r[1] = y1; r[2] = x2; r[3] = y2; r[4] = sc;
        labels[rowbase + t] = lb;
    }
}

extern "C" void kernel_launch(void* const* d_in, const int* in_sizes, int n_in,
                              void* d_out, int out_size, void* d_ws, size_t ws_size,
                              hipStream_t stream) {
    const float* logit    = (const float*)d_in[0];
    const float* boxreg   = (const float*)d_in[1];
    const float* proposal = (const float*)d_in[2];
    const int*   ih       = (const int*)d_in[3];
    const int*   iw       = (const int*)d_in[4];

    char* ws = (char*)d_ws;
    float*  stats    = (float*)(ws + WS_STATS_OFF);
    int*    counters = (int*)(ws + WS_CNT_OFF);
    float*  keys     = (float*)(ws + WS_KEYS_OFF);
    int*    idxs     = (int*)(ws + WS_IDXS_OFF);
    float4* boxes    = (float4*)(ws + WS_BOXES_OFF);

    // K1: 1000 waves (one per row) -> 64000 threads -> 250 blocks of 256
    stats_kernel<<<250, 256, 0, stream>>>(logit, stats, counters);
    // K2: 90000 pairs
    decode_kernel<<<(N_PROP * NCM1 + 255) / 256, 256, 0, stream>>>(
        logit, boxreg, proposal, ih, iw, stats, counters, keys, idxs, boxes);
    // K3: one block per class
    nms_kernel<<<NCM1, 128, 0, stream>>>(counters, keys, idxs, boxes, (float*)d_out);
}

// Round 4
// 84.729 us; speedup vs baseline: 1.5015x; 1.0054x over previous
//
#include <hip/hip_runtime.h>
#include <math.h>

#define N_PROP 1000
#define NCLS   91
#define NCM1   90
#define KDET   100
#define SCORE_TH 0.05f
#define NMS_TH   0.5f
#define MIN_SIZE 1.0f
#define BBOX_CLIP 4.135166556742356f  // log(1000/16)

// ---- workspace layout (bytes) ----
// counters i32[96]            @ 0
// keys     f32[NCM1*N_PROP]   @ 384
// idxs     i32[NCM1*N_PROP]   @ 360384
// boxes    float4[NCM1*N_PROP]@ 720384  (16B aligned)
#define WS_CNT_OFF     0
#define WS_KEYS_OFF    384
#define WS_IDXS_OFF    360384
#define WS_BOXES_OFF   720384

// K0: zero the per-class counters (kernel, not memsetAsync — proven pattern).
__global__ __launch_bounds__(128) void zero_kernel(int* __restrict__ counters) {
    int t = threadIdx.x;
    if (t < NCM1) counters[t] = 0;
}

// K1: fused softmax-stats + decode + filter + per-class compaction.
// One wave per proposal row. Butterfly reductions in fully-converged code;
// per-class logits re-read from global (L1-hot) — no divergent shuffles.
__global__ __launch_bounds__(256) void fused_decode_kernel(
    const float* __restrict__ logit,
    const float* __restrict__ boxreg,
    const float* __restrict__ proposal,
    const int* __restrict__ ih_p,
    const int* __restrict__ iw_p,
    int* __restrict__ counters,
    float* __restrict__ keys,
    int* __restrict__ idxs,
    float4* __restrict__ boxes) {
    const int gid  = blockIdx.x * blockDim.x + threadIdx.x;
    const int row  = gid >> 6;
    const int lane = gid & 63;
    if (row >= N_PROP) return;

    // ---- softmax stats for this row (wave butterfly, fully converged) ----
    const float* p = logit + row * NCLS;
    float l0 = p[lane];                                  // lane < 64 < 91: always valid
    float l1 = (lane + 64 < NCLS) ? p[lane + 64] : -INFINITY;
    float m = fmaxf(l0, l1);
    for (int d = 32; d > 0; d >>= 1) m = fmaxf(m, __shfl_xor(m, d));
    float s = expf(l0 - m) + ((lane + 64 < NCLS) ? expf(l1 - m) : 0.0f);
    for (int d = 32; d > 0; d >>= 1) s += __shfl_xor(s, d);
    const float inv = 1.0f / s;

    // ---- row geometry (uniform across wave) ----
    const float W = (float)(*iw_p);
    const float H = (float)(*ih_p);
    const float4 pr = *(const float4*)(proposal + row * 4);
    const float w  = pr.z - pr.x, h = pr.w - pr.y;
    const float cx = pr.x + 0.5f * w, cy = pr.y + 0.5f * h;

    // ---- decode classes 1..90 across lanes ----
    const float* br = boxreg + (size_t)row * (NCLS * 4);
    for (int c = lane + 1; c < NCLS; c += 64) {
        float lc = p[c];                                 // L1-resident re-read
        float score = expf(lc - m) * inv;

        const float4 d = *(const float4*)(br + c * 4);
        float dx = d.x / 10.0f;
        float dy = d.y / 10.0f;
        float dw = fminf(d.z / 5.0f, BBOX_CLIP);
        float dh = fminf(d.w / 5.0f, BBOX_CLIP);
        float pcx = dx * w + cx, pcy = dy * h + cy;
        float pw  = expf(dw) * w, ph = expf(dh) * h;
        float x1 = pcx - 0.5f * pw, y1 = pcy - 0.5f * ph;
        float x2 = pcx + 0.5f * pw, y2 = pcy + 0.5f * ph;
        x1 = fminf(fmaxf(x1, 0.0f), W);
        x2 = fminf(fmaxf(x2, 0.0f), W);
        y1 = fminf(fmaxf(y1, 0.0f), H);
        y2 = fminf(fmaxf(y2, 0.0f), H);

        bool valid = (score >= SCORE_TH) && ((x2 - x1) >= MIN_SIZE) && ((y2 - y1) >= MIN_SIZE);
        if (valid) {
            int cm1 = c - 1;
            int pos = atomicAdd(&counters[cm1], 1);
            if ((unsigned)pos < N_PROP) {
                int o = cm1 * N_PROP + pos;
                keys[o]  = score;
                idxs[o]  = row;
                boxes[o] = make_float4(x1, y1, x2, y2);
            }
        }
    }
}

// K2: per-class rank-sort (O(V^2), V typically ~20) + greedy NMS + output.
__global__ __launch_bounds__(64) void nms_kernel(
    const int* __restrict__ counters,
    const float* __restrict__ keys,
    const int* __restrict__ idxs,
    const float4* __restrict__ boxes,
    float* __restrict__ out) {
    const int cm1 = blockIdx.x;
    const int tid = threadIdx.x;

    __shared__ float  s_key[N_PROP];
    __shared__ int    s_idx[N_PROP];
    __shared__ float4 s_box[N_PROP];
    __shared__ float  s_skey[N_PROP];
    __shared__ float4 s_sbox[N_PROP];
    __shared__ int    s_keep[N_PROP];
    __shared__ int    s_outpos[KDET];
    __shared__ int    s_nout;

    int V = counters[cm1];
    if (V > N_PROP) V = N_PROP;
    if (V < 0) V = 0;

    for (int t = tid; t < V; t += 64) {
        int o = cm1 * N_PROP + t;
        s_key[t] = keys[o];
        s_idx[t] = idxs[o];
        s_box[t] = boxes[o];
    }
    __syncthreads();

    // rank sort: descending score, ties broken by ascending original index
    for (int t = tid; t < V; t += 64) {
        float kt = s_key[t];
        int   it = s_idx[t];
        int rank = 0;
        for (int j = 0; j < V; ++j) {
            float kj = s_key[j];
            rank += (kj > kt) || (kj == kt && s_idx[j] < it);
        }
        s_skey[rank] = kt;
        s_sbox[rank] = s_box[t];
        s_keep[rank] = 1;
    }
    __syncthreads();

    // greedy NMS over sorted entries
    for (int i = 0; i + 1 < V; ++i) {
        if (s_keep[i]) {
            float4 bi = s_sbox[i];
            float areai = (bi.z - bi.x) * (bi.w - bi.y);
            for (int t = i + 1 + tid; t < V; t += 64) {
                if (s_keep[t]) {
                    float4 bj = s_sbox[t];
                    float lx = fmaxf(bi.x, bj.x), ly = fmaxf(bi.y, bj.y);
                    float rx = fminf(bi.z, bj.z), ry = fminf(bi.w, bj.w);
                    float iw = fmaxf(rx - lx, 0.0f), ihh = fmaxf(ry - ly, 0.0f);
                    float inter = iw * ihh;
                    float areaj = (bj.z - bj.x) * (bj.w - bj.y);
                    float uni = areai + areaj - inter;
                    float iou = inter / fmaxf(uni, 1e-6f);
                    if (iou > NMS_TH) s_keep[t] = 0;
                }
            }
        }
        __syncthreads();
    }

    if (tid == 0) {
        int cnt = 0;
        for (int t = 0; t < V && cnt < KDET; ++t)
            if (s_keep[t]) s_outpos[cnt++] = t;
        s_nout = cnt;
    }
    __syncthreads();
    const int nout = s_nout;

    // write output: dets [9000,5] then labels [9000] (as float)
    float* dets   = out;
    float* labels = out + NCM1 * KDET * 5;
    const int rowbase = cm1 * KDET;
    for (int t = tid; t < KDET; t += 64) {
        float x1 = 0.f, y1 = 0.f, x2 = 0.f, y2 = 0.f, sc = 0.f, lb = 0.f;
        if (t < nout) {
            int p = s_outpos[t];
            float4 b = s_sbox[p];
            x1 = b.x; y1 = b.y; x2 = b.z; y2 = b.w;
            sc = s_skey[p];
            lb = (float)(cm1 + 1);
        }
        float* r = dets + (size_t)(rowbase + t) * 5;
        r[0] = x1; r[1] = y1; r[2] = x2; r[3] = y2; r[4] = sc;
        labels[rowbase + t] = lb;
    }
}

extern "C" void kernel_launch(void* const* d_in, const int* in_sizes, int n_in,
                              void* d_out, int out_size, void* d_ws, size_t ws_size,
                              hipStream_t stream) {
    const float* logit    = (const float*)d_in[0];
    const float* boxreg   = (const float*)d_in[1];
    const float* proposal = (const float*)d_in[2];
    const int*   ih       = (const int*)d_in[3];
    const int*   iw       = (const int*)d_in[4];

    char* ws = (char*)d_ws;
    int*    counters = (int*)(ws + WS_CNT_OFF);
    float*  keys     = (float*)(ws + WS_KEYS_OFF);
    int*    idxs     = (int*)(ws + WS_IDXS_OFF);
    float4* boxes    = (float4*)(ws + WS_BOXES_OFF);

    zero_kernel<<<1, 128, 0, stream>>>(counters);
    // 1000 waves (one per row) -> 64000 threads -> 250 blocks of 256
    fused_decode_kernel<<<250, 256, 0, stream>>>(logit, boxreg, proposal, ih, iw,
                                                 counters, keys, idxs, boxes);
    nms_kernel<<<NCM1, 64, 0, stream>>>(counters, keys, idxs, boxes, (float*)d_out);
}